// Round 3
// baseline (173.552 us; speedup 1.0000x reference)
//
#include <hip/hip_runtime.h>
#include <hip/hip_bf16.h>

// Problem constants (ChebConv_17841294148274)
#define NV      2048          // n_vertex
#define KS      3
#define NNZ_    98304
#define GROWS   49152         // rows in stage-1 GEMM (flat groups of 64)
#define KDIM    64            // contraction dim
#define WCOLS   192           // Ks*c_out
#define MCOLS   1536          // B*T*c_out

__device__ __forceinline__ float b2f(unsigned short h) {
    return __uint_as_float(((unsigned int)h) << 16);
}

__device__ __forceinline__ void store_bf2(unsigned short* p, float f0, float f1) {
    __hip_bfloat162 h;
    h.x = __float2bfloat16(f0);
    h.y = __float2bfloat16(f1);
    *(__hip_bfloat162*)p = h;
}

// ---------------- Dtype probe: are the float inputs f32 or bf16? -----------
// Interpret first 4096 half-words of x as bf16. True-bf16 N(0,1) data has
// exponents in ~[112,130]; f32 data's low half-words are ~uniform random
// bits -> ~38% of exponents fall outside [97,157]. flag=1 means f32 inputs
// (and, per the harness contract, f32 output).
__global__ __launch_bounds__(256) void probe_kernel(
    const unsigned short* __restrict__ xh, int* __restrict__ flag)
{
    __shared__ int s[256];
    int bad = 0;
    const int base = threadIdx.x * 16;
#pragma unroll
    for (int i = 0; i < 16; i++) {
        const unsigned short h = xh[base + i];
        const int e = (h >> 7) & 0xFF;
        if (e < 97 || e > 157) bad++;
    }
    s[threadIdx.x] = bad;
    __syncthreads();
    for (int off = 128; off > 0; off >>= 1) {
        if (threadIdx.x < off) s[threadIdx.x] += s[threadIdx.x + off];
        __syncthreads();
    }
    if (threadIdx.x == 0) flag[0] = (s[0] > 512) ? 1 : 0;
}

// ---------------- Stage 1: Y1[r,j] = sum_i X2[r,i]*W2[i,j]  (49152x192, K=64)
// Block: 256 threads, 32 rows x 192 cols per block. W (48KB) + X tile (8KB) in LDS.
__global__ __launch_bounds__(256) void gemm_kernel(
    const void* __restrict__ xraw, const void* __restrict__ wraw,
    const int* __restrict__ flag, __hip_bfloat16* __restrict__ y1)
{
    __shared__ float Ws[KDIM * WCOLS];   // 12288 f32 = 48 KB
    __shared__ float Xs[32 * KDIM];      // 2048 f32  = 8 KB
    const int tid = threadIdx.x;
    const int r0  = blockIdx.x * 32;

    if (flag[0]) {
        const float* xf = (const float*)xraw;
        const float* wf = (const float*)wraw;
        for (int idx = tid; idx < KDIM * WCOLS; idx += 256) Ws[idx] = wf[idx];
        for (int idx = tid; idx < 32 * KDIM; idx += 256)    Xs[idx] = xf[r0 * KDIM + idx];
    } else {
        const unsigned short* xh = (const unsigned short*)xraw;
        const unsigned short* wh = (const unsigned short*)wraw;
        for (int idx = tid; idx < KDIM * WCOLS; idx += 256) Ws[idx] = b2f(wh[idx]);
        for (int idx = tid; idx < 32 * KDIM; idx += 256)    Xs[idx] = b2f(xh[r0 * KDIM + idx]);
    }
    __syncthreads();

    const int c  = tid & 63;   // col within 64-group (stride-1 in LDS, conflict-free)
    const int rb = tid >> 6;   // 0..3

    float acc[8][3];
#pragma unroll
    for (int rr = 0; rr < 8; rr++) { acc[rr][0] = 0.f; acc[rr][1] = 0.f; acc[rr][2] = 0.f; }

    for (int k = 0; k < KDIM; k++) {
        const float w0 = Ws[k * WCOLS + c];
        const float w1 = Ws[k * WCOLS + c + 64];
        const float w2 = Ws[k * WCOLS + c + 128];
#pragma unroll
        for (int rr = 0; rr < 8; rr++) {
            const float xv = Xs[(rb + 4 * rr) * KDIM + k];
            acc[rr][0] += xv * w0;
            acc[rr][1] += xv * w1;
            acc[rr][2] += xv * w2;
        }
    }
#pragma unroll
    for (int rr = 0; rr < 8; rr++) {
        const int base = (r0 + rb + 4 * rr) * WCOLS;
        y1[base + c      ] = __float2bfloat16(acc[rr][0]);
        y1[base + c + 64 ] = __float2bfloat16(acc[rr][1]);
        y1[base + c + 128] = __float2bfloat16(acc[rr][2]);
    }
}

// ---------------- Sort-by-row machinery (CSR build, every launch) ----------
__global__ __launch_bounds__(256) void count_kernel(
    const int* __restrict__ rows, int* __restrict__ counts)
{
    const int e = blockIdx.x * 256 + threadIdx.x;
    if (e < NNZ_) atomicAdd(&counts[rows[e]], 1);
}

// Single block, 256 threads, 8 counts each -> exclusive offsets[2049] + cursor copy.
__global__ __launch_bounds__(256) void scan_kernel(
    const int* __restrict__ counts, int* __restrict__ offsets, int* __restrict__ cursor)
{
    __shared__ int s[256];
    const int tid = threadIdx.x;
    const int base = tid * 8;
    int c[8];
    int sum = 0;
#pragma unroll
    for (int u = 0; u < 8; u++) { c[u] = counts[base + u]; sum += c[u]; }
    s[tid] = sum;
    __syncthreads();
    for (int off = 1; off < 256; off <<= 1) {
        int v = 0;
        if (tid >= off) v = s[tid - off];
        __syncthreads();
        s[tid] += v;
        __syncthreads();
    }
    int ex = (tid > 0) ? s[tid - 1] : 0;
#pragma unroll
    for (int u = 0; u < 8; u++) {
        offsets[base + u] = ex;
        cursor [base + u] = ex;
        ex += c[u];
    }
    if (tid == 255) offsets[NV] = ex;   // = NNZ_
}

__global__ __launch_bounds__(256) void scatter_kernel(
    const int* __restrict__ rows, const int* __restrict__ cols,
    const void* __restrict__ vraw, const int* __restrict__ flag,
    int* __restrict__ cursor,
    float* __restrict__ sval, int* __restrict__ scol)
{
    const int e = blockIdx.x * 256 + threadIdx.x;
    if (e < NNZ_) {
        const int r = rows[e];
        const int pos = atomicAdd(&cursor[r], 1);
        float v;
        if (flag[0]) v = ((const float*)vraw)[e];
        else         v = b2f(((const unsigned short*)vraw)[e]);
        sval[pos] = v;
        scol[pos] = cols[e] * MCOLS;   // pre-scaled element offset into M
    }
}

// ---------------- Stage 2: SpMM gather. 1 block per output row. ------------
// Each thread owns 6 cols as 3 pairs: j0, j0+1, j0+512, j0+513, j0+1024, j0+1025.
__global__ __launch_bounds__(256) void spmm_kernel(
    const __hip_bfloat16* __restrict__ y1,
    const int* __restrict__ offsets,
    const float* __restrict__ sval, const int* __restrict__ scol,
    const void* __restrict__ braw, const int* __restrict__ flag,
    void* __restrict__ out)
{
    const int r   = blockIdx.x;
    const int tid = threadIdx.x;
    const int start = offsets[r];
    const int end   = offsets[r + 1];
    const int j0 = tid * 2;

    __shared__ float s_val[128];
    __shared__ int   s_col[128];

    float a00 = 0.f, a01 = 0.f, a10 = 0.f, a11 = 0.f, a20 = 0.f, a21 = 0.f;
    const unsigned short* Y = (const unsigned short*)y1;

    for (int base = start; base < end; base += 128) {
        int m = end - base;
        if (m > 128) m = 128;
        if (tid < m) {
            s_val[tid] = sval[base + tid];
            s_col[tid] = scol[base + tid];
        }
        __syncthreads();
        for (int i = 0; i < m; i++) {
            const float v  = s_val[i];
            const int   co = s_col[i] + j0;
            const ushort2 u0 = *(const ushort2*)(Y + co);
            const ushort2 u1 = *(const ushort2*)(Y + co + 512);
            const ushort2 u2 = *(const ushort2*)(Y + co + 1024);
            a00 += v * b2f(u0.x); a01 += v * b2f(u0.y);
            a10 += v * b2f(u1.x); a11 += v * b2f(u1.y);
            a20 += v * b2f(u2.x); a21 += v * b2f(u2.y);
        }
        __syncthreads();
    }

    float b0, b1;
    if (flag[0]) {
        const float* bf = (const float*)braw;
        b0 = bf[ j0      & 63];
        b1 = bf[(j0 + 1) & 63];
    } else {
        const unsigned short* bh = (const unsigned short*)braw;
        b0 = b2f(bh[ j0      & 63]);
        b1 = b2f(bh[(j0 + 1) & 63]);
    }
    const int ob = r * MCOLS + j0;
    if (flag[0]) {
        // f32 output (reference dtype)
        float* O = (float*)out;
        *(float2*)(O + ob       ) = make_float2(a00 + b0, a01 + b1);
        *(float2*)(O + ob + 512 ) = make_float2(a10 + b0, a11 + b1);
        *(float2*)(O + ob + 1024) = make_float2(a20 + b0, a21 + b1);
    } else {
        // bf16 output (converted-dataset world)
        unsigned short* O = (unsigned short*)out;
        store_bf2(O + ob,        a00 + b0, a01 + b1);
        store_bf2(O + ob + 512,  a10 + b0, a11 + b1);
        store_bf2(O + ob + 1024, a20 + b0, a21 + b1);
    }
}

extern "C" void kernel_launch(void* const* d_in, const int* in_sizes, int n_in,
                              void* d_out, int out_size, void* d_ws, size_t ws_size,
                              hipStream_t stream) {
    const void* x    = d_in[0];
    const void* wgt  = d_in[1];
    const void* bias = d_in[2];
    const void* fval = d_in[3];
    const int* frow  = (const int*)d_in[4];
    const int* fcol  = (const int*)d_in[5];

    // Workspace layout (small arrays first, then y1; ~19.7 MB total):
    int* counts  = (int*)d_ws;                       // 2048
    int* offsets = counts + 2048;                    // 2049 (padded to 2064)
    int* cursor  = offsets + 2064;                   // 2048
    int* flag    = cursor + 2048;                    // 16 (padded)
    float* sval  = (float*)(flag + 16);              // 98304
    int*   scol  = (int*)(sval + NNZ_);              // 98304
    __hip_bfloat16* y1 = (__hip_bfloat16*)(scol + NNZ_); // 9,437,184 bf16 = 18.87 MB

    hipMemsetAsync(counts, 0, 2048 * sizeof(int), stream);
    probe_kernel  <<<1,          256, 0, stream>>>((const unsigned short*)x, flag);
    gemm_kernel   <<<GROWS / 32, 256, 0, stream>>>(x, wgt, flag, y1);
    count_kernel  <<<NNZ_ / 256, 256, 0, stream>>>(frow, counts);
    scan_kernel   <<<1,          256, 0, stream>>>(counts, offsets, cursor);
    scatter_kernel<<<NNZ_ / 256, 256, 0, stream>>>(frow, fcol, fval, flag, cursor, sval, scol);
    spmm_kernel   <<<NV,         256, 0, stream>>>(y1, offsets, sval, scol, bias, flag, d_out);
}

// Round 4
// 153.254 us; speedup vs baseline: 1.1324x; 1.1324x over previous
//
#include <hip/hip_runtime.h>
#include <hip/hip_bf16.h>

// Problem constants (ChebConv_17841294148274)
#define NV      2048          // n_vertex
#define NNZ_    98304
#define GROWS   49152         // rows in stage-1 GEMM (flat groups of 64)
#define KDIM    64            // contraction dim
#define WCOLS   192           // Ks*c_out
#define MCOLS   1536          // B*T*c_out

__device__ __forceinline__ float b2f(unsigned short h) {
    return __uint_as_float(((unsigned int)h) << 16);
}

// ---------------- CSR count + dtype probe (block 0) ------------------------
// Probe: interpret first 4096 half-words of x as bf16; f32 data's low halves
// are ~random bits -> ~38% out-of-range exponents. flag=1 => f32 in/out.
__global__ __launch_bounds__(256) void count_probe_kernel(
    const int* __restrict__ rows, int* __restrict__ counts,
    const unsigned short* __restrict__ xh, int* __restrict__ flag)
{
    const int e = blockIdx.x * 256 + threadIdx.x;
    if (e < NNZ_) atomicAdd(&counts[rows[e]], 1);

    if (blockIdx.x == 0) {
        __shared__ int s[256];
        int bad = 0;
        const int base = threadIdx.x * 16;
#pragma unroll
        for (int i = 0; i < 16; i++) {
            const unsigned short h = xh[base + i];
            const int ex = (h >> 7) & 0xFF;
            if (ex < 97 || ex > 157) bad++;
        }
        s[threadIdx.x] = bad;
        __syncthreads();
        for (int off = 128; off > 0; off >>= 1) {
            if (threadIdx.x < off) s[threadIdx.x] += s[threadIdx.x + off];
            __syncthreads();
        }
        if (threadIdx.x == 0) flag[0] = (s[0] > 512) ? 1 : 0;
    }
}

// ---------------- Stage 1: Y1[r,j] = sum_i X2[r,i]*W2[i,j]  (49152x192, K=64)
// Block: 256 thr, 32 rows x 192 cols. Thread tile 4 rows x 6 cols.
// LDS: W 48KB + X 8KB = 56KB -> 2 blocks/CU. VALU-bound (~24 FMA per 10 ds_read-cyc).
__global__ __launch_bounds__(256) void gemm_kernel(
    const void* __restrict__ xraw, const void* __restrict__ wraw,
    const int* __restrict__ flag, __hip_bfloat16* __restrict__ y1)
{
    __shared__ float Ws[KDIM * WCOLS];   // 12288 f32 = 48 KB, layout [k][c]
    __shared__ float Xs[32 * KDIM];      // 2048 f32  = 8 KB,  layout [r][k]
    const int tid = threadIdx.x;
    const int r0  = blockIdx.x * 32;

    if (flag[0]) {
        const float* xf = (const float*)xraw;
        const float* wf = (const float*)wraw;
        for (int idx = tid; idx < KDIM * WCOLS; idx += 256) Ws[idx] = wf[idx];
        for (int idx = tid; idx < 32 * KDIM; idx += 256)    Xs[idx] = xf[r0 * KDIM + idx];
    } else {
        const unsigned short* xh = (const unsigned short*)xraw;
        const unsigned short* wh = (const unsigned short*)wraw;
        for (int idx = tid; idx < KDIM * WCOLS; idx += 256) Ws[idx] = b2f(wh[idx]);
        for (int idx = tid; idx < 32 * KDIM; idx += 256)    Xs[idx] = b2f(xh[r0 * KDIM + idx]);
    }
    __syncthreads();

    const int c  = tid & 31;   // col base (stride-1 lanes -> conflict-free, 2-way broadcast)
    const int rg = tid >> 5;   // 0..7; rows rg+8*rr

    float acc[4][6];
#pragma unroll
    for (int rr = 0; rr < 4; rr++)
#pragma unroll
        for (int t = 0; t < 6; t++) acc[rr][t] = 0.f;

    for (int k4 = 0; k4 < KDIM; k4 += 4) {
        float4 xv[4];
#pragma unroll
        for (int rr = 0; rr < 4; rr++)
            xv[rr] = *(const float4*)&Xs[(rg + 8 * rr) * KDIM + k4];   // b128, broadcast
#pragma unroll
        for (int kk = 0; kk < 4; kk++) {
            float wv[6];
#pragma unroll
            for (int t = 0; t < 6; t++) wv[t] = Ws[(k4 + kk) * WCOLS + c + 32 * t];
#pragma unroll
            for (int rr = 0; rr < 4; rr++) {
                const float xx = (&xv[rr].x)[kk];
#pragma unroll
                for (int t = 0; t < 6; t++) acc[rr][t] += xx * wv[t];
            }
        }
    }
#pragma unroll
    for (int rr = 0; rr < 4; rr++) {
        const int base = (r0 + rg + 8 * rr) * WCOLS + c;
#pragma unroll
        for (int t = 0; t < 6; t++)
            y1[base + 32 * t] = __float2bfloat16(acc[rr][t]);
    }
}

// Single block, 256 threads, 8 counts each -> exclusive offsets[2049] + cursor copy.
__global__ __launch_bounds__(256) void scan_kernel(
    const int* __restrict__ counts, int* __restrict__ offsets, int* __restrict__ cursor)
{
    __shared__ int s[256];
    const int tid = threadIdx.x;
    const int base = tid * 8;
    int c[8];
    int sum = 0;
#pragma unroll
    for (int u = 0; u < 8; u++) { c[u] = counts[base + u]; sum += c[u]; }
    s[tid] = sum;
    __syncthreads();
    for (int off = 1; off < 256; off <<= 1) {
        int v = 0;
        if (tid >= off) v = s[tid - off];
        __syncthreads();
        s[tid] += v;
        __syncthreads();
    }
    int ex = (tid > 0) ? s[tid - 1] : 0;
#pragma unroll
    for (int u = 0; u < 8; u++) {
        offsets[base + u] = ex;
        cursor [base + u] = ex;
        ex += c[u];
    }
    if (tid == 255) offsets[NV] = ex;   // = NNZ_
}

// Scatter edges into row-sorted order as packed int2 {col*MCOLS, valbits}.
__global__ __launch_bounds__(256) void scatter_kernel(
    const int* __restrict__ rows, const int* __restrict__ cols,
    const void* __restrict__ vraw, const int* __restrict__ flag,
    int* __restrict__ cursor, int2* __restrict__ sedge)
{
    const int e = blockIdx.x * 256 + threadIdx.x;
    if (e < NNZ_) {
        const int r = rows[e];
        const int pos = atomicAdd(&cursor[r], 1);
        float v;
        if (flag[0]) v = ((const float*)vraw)[e];
        else         v = b2f(((const unsigned short*)vraw)[e]);
        sedge[pos] = make_int2(cols[e] * MCOLS, __float_as_int(v));
    }
}

// ---------------- Stage 2: SpMM gather, XCD-slab partitioned. --------------
// Grid 16384 = 2048 rows x 8 col-slabs of 192. slab = blockIdx&7 -> pins each
// slab to one XCD (round-robin dispatch) so the slab's y1 working set
// (6144x192x2B = 2.36MB) stays resident in that XCD's 4MB L2.
// 64 threads, 3 cols each (lane, lane+64, lane+128). bias idx = lane (192%64==0).
__global__ __launch_bounds__(64) void spmm_kernel(
    const __hip_bfloat16* __restrict__ y1,
    const int* __restrict__ offsets,
    const int2* __restrict__ sedge,
    const void* __restrict__ braw, const int* __restrict__ flag,
    void* __restrict__ out)
{
    const int b    = blockIdx.x;
    const int slab = b & 7;
    const int row  = b >> 3;
    const int lane = threadIdx.x;
    const int start = offsets[row];
    const int end   = offsets[row + 1];
    const int cb = slab * WCOLS + lane;   // base col

    __shared__ int2 se[64];
    float a0 = 0.f, a1 = 0.f, a2 = 0.f;
    const unsigned short* Y = (const unsigned short*)y1;

    for (int base = start; base < end; base += 64) {
        int m = end - base;
        if (m > 64) m = 64;
        if (lane < m) se[lane] = sedge[base + lane];
        __syncthreads();
        for (int i = 0; i < m; i++) {
            const int2 e = se[i];
            const float v = __int_as_float(e.y);
            const int co = e.x + cb;
            a0 += v * b2f(Y[co      ]);
            a1 += v * b2f(Y[co + 64 ]);
            a2 += v * b2f(Y[co + 128]);
        }
        __syncthreads();
    }

    float bb;
    if (flag[0]) bb = ((const float*)braw)[lane];
    else         bb = b2f(((const unsigned short*)braw)[lane]);

    const int ob = row * MCOLS + cb;
    if (flag[0]) {
        float* O = (float*)out;
        O[ob      ] = a0 + bb;
        O[ob + 64 ] = a1 + bb;
        O[ob + 128] = a2 + bb;
    } else {
        unsigned short* O = (unsigned short*)out;
        O[ob      ] = (unsigned short)(__bfloat16_as_ushort(__float2bfloat16(a0 + bb)));
        O[ob + 64 ] = (unsigned short)(__bfloat16_as_ushort(__float2bfloat16(a1 + bb)));
        O[ob + 128] = (unsigned short)(__bfloat16_as_ushort(__float2bfloat16(a2 + bb)));
    }
}

extern "C" void kernel_launch(void* const* d_in, const int* in_sizes, int n_in,
                              void* d_out, int out_size, void* d_ws, size_t ws_size,
                              hipStream_t stream) {
    const void* x    = d_in[0];
    const void* wgt  = d_in[1];
    const void* bias = d_in[2];
    const void* fval = d_in[3];
    const int* frow  = (const int*)d_in[4];
    const int* fcol  = (const int*)d_in[5];

    // Workspace layout:
    int* counts  = (int*)d_ws;                       // 2048
    int* offsets = counts + 2048;                    // 2049 (padded to 2064)
    int* cursor  = offsets + 2064;                   // 2048
    int* flag    = cursor + 2048;                    // 16 (padded)
    int2* sedge  = (int2*)(flag + 16);               // 98304 int2 = 786 KB
    __hip_bfloat16* y1 = (__hip_bfloat16*)(sedge + NNZ_); // 9,437,184 bf16 = 18.87 MB

    hipMemsetAsync(counts, 0, 2048 * sizeof(int), stream);
    count_probe_kernel<<<NNZ_ / 256, 256, 0, stream>>>(frow, counts,
                                                       (const unsigned short*)x, flag);
    gemm_kernel   <<<GROWS / 32, 256, 0, stream>>>(x, wgt, flag, y1);
    scan_kernel   <<<1,          256, 0, stream>>>(counts, offsets, cursor);
    scatter_kernel<<<NNZ_ / 256, 256, 0, stream>>>(frow, fcol, fval, flag, cursor, sedge);
    spmm_kernel   <<<NV * 8,     64,  0, stream>>>(y1, offsets, sedge, bias, flag, d_out);
}